// Round 1
// baseline (436.934 us; speedup 1.0000x reference)
//
#include <hip/hip_runtime.h>

// ud_MultiheadSoftmaxAttention: B=2 T=2048 D=1024 H=16 hd=64
// Pipeline: prep(fp32->bf16 + row scales) -> batched QKV GEMM (bf16 MFMA)
//           -> V transpose -> flash attention -> output GEMM.
// Note: per-query additive score biases (logvar/w_phi terms) cancel in softmax;
// only the per-row temperature 1/(8*max(mean(phi),1e-6)) survives.

typedef __bf16 bf16x8 __attribute__((ext_vector_type(8)));
typedef float f32x4 __attribute__((ext_vector_type(4)));
typedef unsigned short u16;
typedef unsigned int u32;
typedef u16 u16x8 __attribute__((ext_vector_type(8)));

#define GLD_TO_LDS(g, l) __builtin_amdgcn_global_load_lds( \
    (const __attribute__((address_space(1))) void*)(g),    \
    (__attribute__((address_space(3))) void*)(l), 16, 0, 0)

__device__ __forceinline__ u16 f2b(float f) {
  u32 u = __builtin_bit_cast(u32, f);
  u += 0x7fffu + ((u >> 16) & 1u);   // RNE
  return (u16)(u >> 16);
}

// ---------------- prep: fp32 -> bf16 conversions + softmax row scales ----
__global__ __launch_bounds__(256) void prep_kernel(
    const float* __restrict__ query, const float* __restrict__ key,
    const float* __restrict__ value, const float* __restrict__ Wq,
    const float* __restrict__ Wk, const float* __restrict__ Wv,
    const float* __restrict__ Wo, const float* __restrict__ phi,
    u16* __restrict__ Xq, u16* __restrict__ Xk, u16* __restrict__ Xv,
    u16* __restrict__ Wqb, u16* __restrict__ Wkb, u16* __restrict__ Wvb,
    u16* __restrict__ Wob, float* __restrict__ rscale)
{
  const long gid = (long)blockIdx.x * 256 + threadIdx.x;  // 0..4M-1
  const long e = gid * 4;
  const float* src; u16* dst; long off;
  if (e < 4194304L)       { src = query; dst = Xq;  off = e; }
  else if (e < 8388608L)  { src = key;   dst = Xk;  off = e - 4194304L; }
  else if (e < 12582912L) { src = value; dst = Xv;  off = e - 8388608L; }
  else if (e < 13631488L) { src = Wq;    dst = Wqb; off = e - 12582912L; }
  else if (e < 14680064L) { src = Wk;    dst = Wkb; off = e - 13631488L; }
  else if (e < 15728640L) { src = Wv;    dst = Wvb; off = e - 14680064L; }
  else                    { src = Wo;    dst = Wob; off = e - 15728640L; }
  const float4 v = *(const float4*)(src + off);
  ushort4 o;
  o.x = f2b(v.x); o.y = f2b(v.y); o.z = f2b(v.z); o.w = f2b(v.w);
  *(ushort4*)(dst + off) = o;

  if (gid < 4096) {  // per-token softmax temperature (log2e folded in)
    const float4 p0 = *(const float4*)(phi + gid * 8);
    const float4 p1 = *(const float4*)(phi + gid * 8 + 4);
    const float mean = (p0.x + p0.y + p0.z + p0.w + p1.x + p1.y + p1.z + p1.w) * 0.125f;
    rscale[gid] = 1.4426950408889634f / (8.0f * fmaxf(mean, 1e-6f));
  }
}

// ---------------- GEMM: C[m][n] = A[m][:] . Bw[n][:] + bias[n] -----------
// 128x128 tile, BK=32, 256 thr (4 waves 2x2), global_load_lds width-16.
// MODE 0: bf16 out in per-head layout [b][h][t][64]; MODE 1: f32 flat out.
template<int MODE>
__device__ __forceinline__ void gemm_body(
    u16* As, u16* Bs,
    const u16* __restrict__ A, const u16* __restrict__ Bw,
    const float* __restrict__ bias, void* __restrict__ Cout)
{
  constexpr int K = 1024;
  const int t = threadIdx.x;
  const int lane = t & 63, w = t >> 6;
  const int g = lane >> 4, c = lane & 15;
  const int m0 = blockIdx.y * 128, n0 = blockIdx.x * 128;
  const int srow = t >> 2, skc = (t & 3) * 8;
  const u16* gA = A + (size_t)(m0 + srow) * K + skc;
  const u16* gB = Bw + (size_t)(n0 + srow) * K + skc;
  u16* ldsA = As + w * 512;   // wave-uniform base; HW adds lane*16B
  u16* ldsB = Bs + w * 512;
  const int wm = (w >> 1) * 64, wn = (w & 1) * 64;

  f32x4 acc[4][4] = {};

  for (int k0 = 0; k0 < K; k0 += 32) {
    GLD_TO_LDS(gA + k0, ldsA);
    GLD_TO_LDS(gA + 64 * K + k0, ldsA + 2048);
    GLD_TO_LDS(gB + k0, ldsB);
    GLD_TO_LDS(gB + 64 * K + k0, ldsB + 2048);
    __syncthreads();
    bf16x8 af[4], bfr[4];
#pragma unroll
    for (int mi = 0; mi < 4; ++mi)
      af[mi] = *(const bf16x8*)(As + (wm + mi * 16 + c) * 32 + g * 8);
#pragma unroll
    for (int ni = 0; ni < 4; ++ni)
      bfr[ni] = *(const bf16x8*)(Bs + (wn + ni * 16 + c) * 32 + g * 8);
#pragma unroll
    for (int mi = 0; mi < 4; ++mi)
#pragma unroll
      for (int ni = 0; ni < 4; ++ni)
        acc[mi][ni] = __builtin_amdgcn_mfma_f32_16x16x32_bf16(
            af[mi], bfr[ni], acc[mi][ni], 0, 0, 0);
    __syncthreads();
  }

#pragma unroll
  for (int ni = 0; ni < 4; ++ni) {
    const int ncol = n0 + wn + ni * 16 + c;
    const float bv = bias[ncol];
#pragma unroll
    for (int mi = 0; mi < 4; ++mi) {
#pragma unroll
      for (int r = 0; r < 4; ++r) {
        const int mrow = m0 + wm + mi * 16 + g * 4 + r;  // C/D: col=lane&15, row=(lane>>4)*4+r
        const float val = acc[mi][ni][r] + bv;
        if (MODE == 0) {
          const int bb = mrow >> 11, tt = mrow & 2047;
          const int hh = ncol >> 6, dd = ncol & 63;
          ((u16*)Cout)[((((size_t)bb * 16 + hh) * 2048 + tt) << 6) + dd] = f2b(val);
        } else {
          ((float*)Cout)[(size_t)mrow * 1024 + ncol] = val;
        }
      }
    }
  }
}

__global__ __launch_bounds__(256) void gemm_qkv_kernel(
    const u16* __restrict__ Xq, const u16* __restrict__ Xk, const u16* __restrict__ Xv,
    const u16* __restrict__ Wqb, const u16* __restrict__ Wkb, const u16* __restrict__ Wvb,
    const float* __restrict__ bq, const float* __restrict__ bk, const float* __restrict__ bv,
    u16* __restrict__ Qh, u16* __restrict__ Kh, u16* __restrict__ Vh)
{
  __shared__ __align__(16) u16 As[4096], Bs[4096];
  const int z = blockIdx.z;
  const u16* A = (z == 0) ? Xq : (z == 1) ? Xk : Xv;
  const u16* W = (z == 0) ? Wqb : (z == 1) ? Wkb : Wvb;
  const float* bias = (z == 0) ? bq : (z == 1) ? bk : bv;
  u16* C = (z == 0) ? Qh : (z == 1) ? Kh : Vh;
  gemm_body<0>(As, Bs, A, W, bias, C);
}

__global__ __launch_bounds__(256) void gemm_o_kernel(
    const u16* __restrict__ Oh, const u16* __restrict__ Wob,
    const float* __restrict__ bo, float* __restrict__ out)
{
  __shared__ __align__(16) u16 As[4096], Bs[4096];
  gemm_body<1>(As, Bs, Oh, Wob, bo, out);
}

// ---------------- V transpose: [bh][t][64] -> [bh][64][t] ----------------
__global__ __launch_bounds__(256) void transpose_v_kernel(
    const u16* __restrict__ Vh, u16* __restrict__ Vt)
{
  __shared__ __align__(16) u16 tile[64][72];
  const int bh = blockIdx.y, t0 = blockIdx.x * 64;
  const int tid = threadIdx.x;
  const int r = tid >> 3, cc = (tid & 7) * 8;
  const u16* src = Vh + ((size_t)bh * 2048 + t0) * 64;
#pragma unroll
  for (int it = 0; it < 2; ++it)
    *(u16x8*)&tile[r + 32 * it][cc] = *(const u16x8*)(src + (size_t)(r + 32 * it) * 64 + cc);
  __syncthreads();
  u16* dst = Vt + (size_t)bh * 64 * 2048 + t0;
#pragma unroll
  for (int it = 0; it < 2; ++it) {
    const int d = r + 32 * it;
    u16x8 v;
#pragma unroll
    for (int j = 0; j < 8; ++j) v[j] = tile[cc + j][d];
    *(u16x8*)(dst + (size_t)d * 2048 + cc) = v;
  }
}

// ---------------- flash attention ----------------------------------------
// grid (T/64, B*H), 256 thr = 4 independent waves, 16 q-rows each.
// K/V read straight from L2 (256KB/head); P bounced via per-wave LDS.
__global__ __launch_bounds__(256) void attn_kernel(
    const u16* __restrict__ Qh, const u16* __restrict__ Kh,
    const u16* __restrict__ Vt, const float* __restrict__ rscale,
    u16* __restrict__ Oh)
{
  __shared__ __align__(16) u16 Pl[4][16][40];  // [wave][qrow][key] pad->80B rows
  const int bh = blockIdx.y;
  const int b = bh >> 4, h = bh & 15;
  const int t = threadIdx.x;
  const int w = t >> 6, lane = t & 63;
  const int g = lane >> 4, c = lane & 15;
  const int q0 = blockIdx.x * 64 + w * 16;

  const u16* Qb = Qh + (size_t)bh * (2048 * 64);
  const u16* Kb = Kh + (size_t)bh * (2048 * 64);
  const u16* Vb = Vt + (size_t)bh * (64 * 2048);

  // A-frag: row=lane&15 (q), k=(lane>>4)*8+j (d)
  const bf16x8 qf0 = *(const bf16x8*)(Qb + (size_t)(q0 + c) * 64 + g * 8);
  const bf16x8 qf1 = *(const bf16x8*)(Qb + (size_t)(q0 + c) * 64 + 32 + g * 8);

  float rsc[4], m[4], l[4];
#pragma unroll
  for (int r = 0; r < 4; ++r) {
    rsc[r] = rscale[b * 2048 + q0 + g * 4 + r];  // rows of D layout
    m[r] = -3.0e38f;
    l[r] = 0.0f;
  }
  f32x4 acc[4] = {};
  u16 (* const Pw)[40] = Pl[w];

  for (int kc = 0; kc < 2048; kc += 32) {
    // B-frag for QK^T: col=lane&15 (key), k=(lane>>4)*8+j (d)
    const u16* Kp = Kb + (size_t)(kc + c) * 64 + g * 8;
    const bf16x8 k00 = *(const bf16x8*)(Kp);
    const bf16x8 k01 = *(const bf16x8*)(Kp + 32);
    const bf16x8 k10 = *(const bf16x8*)(Kp + 16 * 64);
    const bf16x8 k11 = *(const bf16x8*)(Kp + 16 * 64 + 32);
    const f32x4 z = {};
    f32x4 s0 = __builtin_amdgcn_mfma_f32_16x16x32_bf16(qf0, k00, z, 0, 0, 0);
    s0 = __builtin_amdgcn_mfma_f32_16x16x32_bf16(qf1, k01, s0, 0, 0, 0);
    f32x4 s1 = __builtin_amdgcn_mfma_f32_16x16x32_bf16(qf0, k10, z, 0, 0, 0);
    s1 = __builtin_amdgcn_mfma_f32_16x16x32_bf16(qf1, k11, s1, 0, 0, 0);

    float tmax[4];
#pragma unroll
    for (int r = 0; r < 4; ++r) {
      s0[r] *= rsc[r];
      s1[r] *= rsc[r];
      tmax[r] = fmaxf(s0[r], s1[r]);
    }
#pragma unroll
    for (int d = 1; d < 16; d <<= 1)
#pragma unroll
      for (int r = 0; r < 4; ++r)
        tmax[r] = fmaxf(tmax[r], __shfl_xor(tmax[r], d));

    float corr[4], rsum[4], p0[4], p1[4];
#pragma unroll
    for (int r = 0; r < 4; ++r) {
      const float mn = fmaxf(m[r], tmax[r]);
      corr[r] = __builtin_amdgcn_exp2f(m[r] - mn);
      p0[r] = __builtin_amdgcn_exp2f(s0[r] - mn);
      p1[r] = __builtin_amdgcn_exp2f(s1[r] - mn);
      rsum[r] = p0[r] + p1[r];
      m[r] = mn;
    }
#pragma unroll
    for (int d = 1; d < 16; d <<= 1)
#pragma unroll
      for (int r = 0; r < 4; ++r)
        rsum[r] += __shfl_xor(rsum[r], d);
#pragma unroll
    for (int r = 0; r < 4; ++r)
      l[r] = l[r] * corr[r] + rsum[r];
#pragma unroll
    for (int dt = 0; dt < 4; ++dt)
#pragma unroll
      for (int r = 0; r < 4; ++r)
        acc[dt][r] *= corr[r];

    // D layout (row=g*4+r, col=c) -> LDS -> A-frag layout (same-wave, no barrier)
#pragma unroll
    for (int r = 0; r < 4; ++r) {
      Pw[g * 4 + r][c] = f2b(p0[r]);
      Pw[g * 4 + r][16 + c] = f2b(p1[r]);
    }
    const bf16x8 pA = *(const bf16x8*)&Pw[c][g * 8];
#pragma unroll
    for (int dt = 0; dt < 4; ++dt) {
      // B-frag for PV: col=c (out dim), k=(g*8+j) (key); Vt contiguous in key
      const bf16x8 vf = *(const bf16x8*)(Vb + (size_t)(dt * 16 + c) * 2048 + kc + g * 8);
      acc[dt] = __builtin_amdgcn_mfma_f32_16x16x32_bf16(pA, vf, acc[dt], 0, 0, 0);
    }
  }

  float inv[4];
#pragma unroll
  for (int r = 0; r < 4; ++r) inv[r] = 1.0f / l[r];
#pragma unroll
  for (int dt = 0; dt < 4; ++dt)
#pragma unroll
    for (int r = 0; r < 4; ++r) {
      const int trow = q0 + g * 4 + r;
      const int dd = dt * 16 + c;
      // Oh layout [b][t][h][d] == flat [m][1024] for the output GEMM
      Oh[(((size_t)b * 2048 + trow) * 16 + h) * 64 + dd] = f2b(acc[dt][r] * inv[r]);
    }
}

// ---------------- launch --------------------------------------------------
extern "C" void kernel_launch(void* const* d_in, const int* in_sizes, int n_in,
                              void* d_out, int out_size, void* d_ws, size_t ws_size,
                              hipStream_t stream) {
  const float* query = (const float*)d_in[0];
  const float* key_  = (const float*)d_in[1];
  const float* value = (const float*)d_in[2];
  const float* phi   = (const float*)d_in[3];
  // d_in[4] logvar: cancels in softmax (additive per-query bias)
  const float* Wq = (const float*)d_in[5];
  const float* bq = (const float*)d_in[6];
  const float* Wk = (const float*)d_in[7];
  const float* bk = (const float*)d_in[8];
  const float* Wv = (const float*)d_in[9];
  const float* bv = (const float*)d_in[10];
  const float* Wo = (const float*)d_in[11];
  const float* bo = (const float*)d_in[12];
  // d_in[13] w_sigma, d_in[14] w_phi: cancel in softmax

  char* ws = (char*)d_ws;
  const size_t MB = 1u << 20;
  u16* Xq  = (u16*)(ws);             // 8MB; reused as Oh after QKV GEMM
  u16* Xk  = (u16*)(ws + 8 * MB);    // 8MB; reused as Vt after QKV GEMM
  u16* Xv  = (u16*)(ws + 16 * MB);   // 8MB
  u16* Wqb = (u16*)(ws + 24 * MB);   // 2MB each
  u16* Wkb = (u16*)(ws + 26 * MB);
  u16* Wvb = (u16*)(ws + 28 * MB);
  u16* Wob = (u16*)(ws + 30 * MB);
  u16* Qh  = (u16*)(ws + 32 * MB);   // 8MB each
  u16* Kh  = (u16*)(ws + 40 * MB);
  u16* Vh  = (u16*)(ws + 48 * MB);
  float* rscale = (float*)(ws + 56 * MB);  // 16KB
  u16* Oh = Xq;
  u16* Vt = Xk;

  prep_kernel<<<16384, 256, 0, stream>>>(query, key_, value, Wq, Wk, Wv, Wo, phi,
                                         Xq, Xk, Xv, Wqb, Wkb, Wvb, Wob, rscale);
  gemm_qkv_kernel<<<dim3(8, 32, 3), 256, 0, stream>>>(Xq, Xk, Xv, Wqb, Wkb, Wvb,
                                                      bq, bk, bv, Qh, Kh, Vh);
  transpose_v_kernel<<<dim3(32, 32), 256, 0, stream>>>(Vh, Vt);
  attn_kernel<<<dim3(32, 32), 256, 0, stream>>>(Qh, Kh, Vt, rscale, Oh);
  gemm_o_kernel<<<dim3(8, 32), 256, 0, stream>>>(Oh, Wob, bo, (float*)d_out);
}

// Round 2
// 434.168 us; speedup vs baseline: 1.0064x; 1.0064x over previous
//
#include <hip/hip_runtime.h>

// ud_MultiheadSoftmaxAttention: B=2 T=2048 D=1024 H=16 hd=64
// Pipeline: prep(fp32->bf16 + row scales) -> batched QKV GEMM (bf16 MFMA)
//           -> V transpose -> flash attention -> output GEMM.
// Note: per-query additive score biases (logvar/w_phi terms) cancel in softmax;
// only the per-row temperature 1/(8*max(mean(phi),1e-6)) survives.

typedef __bf16 bf16x8 __attribute__((ext_vector_type(8)));
typedef float f32x4 __attribute__((ext_vector_type(4)));
typedef unsigned short u16;
typedef unsigned int u32;
typedef u16 u16x8 __attribute__((ext_vector_type(8)));

#define GLD_TO_LDS(g, l) __builtin_amdgcn_global_load_lds( \
    (const __attribute__((address_space(1))) void*)(g),    \
    (__attribute__((address_space(3))) void*)(l), 16, 0, 0)

__device__ __forceinline__ u16 f2b(float f) {
  u32 u = __builtin_bit_cast(u32, f);
  u += 0x7fffu + ((u >> 16) & 1u);   // RNE
  return (u16)(u >> 16);
}

// ---------------- prep: fp32 -> bf16 conversions + softmax row scales ----
__global__ __launch_bounds__(256) void prep_kernel(
    const float* __restrict__ query, const float* __restrict__ key,
    const float* __restrict__ value, const float* __restrict__ Wq,
    const float* __restrict__ Wk, const float* __restrict__ Wv,
    const float* __restrict__ Wo, const float* __restrict__ phi,
    u16* __restrict__ Xq, u16* __restrict__ Xk, u16* __restrict__ Xv,
    u16* __restrict__ Wqb, u16* __restrict__ Wkb, u16* __restrict__ Wvb,
    u16* __restrict__ Wob, float* __restrict__ rscale)
{
  const long gid = (long)blockIdx.x * 256 + threadIdx.x;  // 0..4M-1
  const long e = gid * 4;
  const float* src; u16* dst; long off;
  if (e < 4194304L)       { src = query; dst = Xq;  off = e; }
  else if (e < 8388608L)  { src = key;   dst = Xk;  off = e - 4194304L; }
  else if (e < 12582912L) { src = value; dst = Xv;  off = e - 8388608L; }
  else if (e < 13631488L) { src = Wq;    dst = Wqb; off = e - 12582912L; }
  else if (e < 14680064L) { src = Wk;    dst = Wkb; off = e - 13631488L; }
  else if (e < 15728640L) { src = Wv;    dst = Wvb; off = e - 14680064L; }
  else                    { src = Wo;    dst = Wob; off = e - 15728640L; }
  const float4 v = *(const float4*)(src + off);
  ushort4 o;
  o.x = f2b(v.x); o.y = f2b(v.y); o.z = f2b(v.z); o.w = f2b(v.w);
  *(ushort4*)(dst + off) = o;

  if (gid < 4096) {  // per-token softmax temperature (log2e folded in)
    const float4 p0 = *(const float4*)(phi + gid * 8);
    const float4 p1 = *(const float4*)(phi + gid * 8 + 4);
    const float mean = (p0.x + p0.y + p0.z + p0.w + p1.x + p1.y + p1.z + p1.w) * 0.125f;
    rscale[gid] = 1.4426950408889634f / (8.0f * fmaxf(mean, 1e-6f));
  }
}

// ---------------- GEMM: C[m][n] = A[m][:] . Bw[n][:] + bias[n] -----------
// 128x128 tile, BK=32, 256 thr (4 waves 2x2), global_load_lds width-16.
// MODE 0: bf16 out in per-head layout [b][h][t][64]; MODE 1: f32 flat out.
template<int MODE>
__device__ __forceinline__ void gemm_body(
    u16* As, u16* Bs,
    const u16* __restrict__ A, const u16* __restrict__ Bw,
    const float* __restrict__ bias, void* __restrict__ Cout)
{
  constexpr int K = 1024;
  const int t = threadIdx.x;
  const int lane = t & 63, w = t >> 6;
  const int g = lane >> 4, c = lane & 15;
  const int m0 = blockIdx.y * 128, n0 = blockIdx.x * 128;
  const int srow = t >> 2, skc = (t & 3) * 8;
  const u16* gA = A + (size_t)(m0 + srow) * K + skc;
  const u16* gB = Bw + (size_t)(n0 + srow) * K + skc;
  u16* ldsA = As + w * 512;   // wave-uniform base; HW adds lane*16B
  u16* ldsB = Bs + w * 512;
  const int wm = (w >> 1) * 64, wn = (w & 1) * 64;

  f32x4 acc[4][4] = {};

  for (int k0 = 0; k0 < K; k0 += 32) {
    GLD_TO_LDS(gA + k0, ldsA);
    GLD_TO_LDS(gA + 64 * K + k0, ldsA + 2048);
    GLD_TO_LDS(gB + k0, ldsB);
    GLD_TO_LDS(gB + 64 * K + k0, ldsB + 2048);
    __syncthreads();
    bf16x8 af[4], bfr[4];
#pragma unroll
    for (int mi = 0; mi < 4; ++mi)
      af[mi] = *(const bf16x8*)(As + (wm + mi * 16 + c) * 32 + g * 8);
#pragma unroll
    for (int ni = 0; ni < 4; ++ni)
      bfr[ni] = *(const bf16x8*)(Bs + (wn + ni * 16 + c) * 32 + g * 8);
#pragma unroll
    for (int mi = 0; mi < 4; ++mi)
#pragma unroll
      for (int ni = 0; ni < 4; ++ni)
        acc[mi][ni] = __builtin_amdgcn_mfma_f32_16x16x32_bf16(
            af[mi], bfr[ni], acc[mi][ni], 0, 0, 0);
    __syncthreads();
  }

#pragma unroll
  for (int ni = 0; ni < 4; ++ni) {
    const int ncol = n0 + wn + ni * 16 + c;
    const float bv = bias[ncol];
#pragma unroll
    for (int mi = 0; mi < 4; ++mi) {
#pragma unroll
      for (int r = 0; r < 4; ++r) {
        const int mrow = m0 + wm + mi * 16 + g * 4 + r;  // C/D: col=lane&15, row=(lane>>4)*4+r
        const float val = acc[mi][ni][r] + bv;
        if (MODE == 0) {
          const int bb = mrow >> 11, tt = mrow & 2047;
          const int hh = ncol >> 6, dd = ncol & 63;
          ((u16*)Cout)[((((size_t)bb * 16 + hh) * 2048 + tt) << 6) + dd] = f2b(val);
        } else {
          ((float*)Cout)[(size_t)mrow * 1024 + ncol] = val;
        }
      }
    }
  }
}

__global__ __launch_bounds__(256) void gemm_qkv_kernel(
    const u16* __restrict__ Xq, const u16* __restrict__ Xk, const u16* __restrict__ Xv,
    const u16* __restrict__ Wqb, const u16* __restrict__ Wkb, const u16* __restrict__ Wvb,
    const float* __restrict__ bq, const float* __restrict__ bk, const float* __restrict__ bv,
    u16* __restrict__ Qh, u16* __restrict__ Kh, u16* __restrict__ Vh)
{
  __shared__ __align__(16) u16 As[4096], Bs[4096];
  const int z = blockIdx.z;
  const u16* A = (z == 0) ? Xq : (z == 1) ? Xk : Xv;
  const u16* W = (z == 0) ? Wqb : (z == 1) ? Wkb : Wvb;
  const float* bias = (z == 0) ? bq : (z == 1) ? bk : bv;
  u16* C = (z == 0) ? Qh : (z == 1) ? Kh : Vh;
  gemm_body<0>(As, Bs, A, W, bias, C);
}

__global__ __launch_bounds__(256) void gemm_o_kernel(
    const u16* __restrict__ Oh, const u16* __restrict__ Wob,
    const float* __restrict__ bo, float* __restrict__ out)
{
  __shared__ __align__(16) u16 As[4096], Bs[4096];
  gemm_body<1>(As, Bs, Oh, Wob, bo, out);
}

// ---------------- V transpose: [bh][t][64] -> [bh][64][t] ----------------
__global__ __launch_bounds__(256) void transpose_v_kernel(
    const u16* __restrict__ Vh, u16* __restrict__ Vt)
{
  __shared__ __align__(16) u16 tile[64][72];
  const int bh = blockIdx.y, t0 = blockIdx.x * 64;
  const int tid = threadIdx.x;
  const int r = tid >> 3, cc = (tid & 7) * 8;
  const u16* src = Vh + ((size_t)bh * 2048 + t0) * 64;
#pragma unroll
  for (int it = 0; it < 2; ++it)
    *(u16x8*)&tile[r + 32 * it][cc] = *(const u16x8*)(src + (size_t)(r + 32 * it) * 64 + cc);
  __syncthreads();
  u16* dst = Vt + (size_t)bh * 64 * 2048 + t0;
#pragma unroll
  for (int it = 0; it < 2; ++it) {
    const int d = r + 32 * it;
    u16x8 v;
#pragma unroll
    for (int j = 0; j < 8; ++j) v[j] = tile[cc + j][d];
    *(u16x8*)(dst + (size_t)d * 2048 + cc) = v;
  }
}

// ---------------- flash attention ----------------------------------------
// grid (T/64, B*H), 256 thr = 4 independent waves, 16 q-rows each, KB=64.
// Defer-max (THR=8): cross-lane max tree only when a lane-local max exceeds
// running max by >8 (wave-uniform __any branch). Row-sum l kept lane-local,
// reduced ONCE at the end. Both per-tile shuffle trees removed from hot loop.
__global__ __launch_bounds__(256) void attn_kernel(
    const u16* __restrict__ Qh, const u16* __restrict__ Kh,
    const u16* __restrict__ Vt, const float* __restrict__ rscale,
    u16* __restrict__ Oh)
{
  __shared__ __align__(16) u16 Pl[4][16][72];  // [wave][qrow][64 keys + pad]
  const int bh = blockIdx.y;
  const int b = bh >> 4, h = bh & 15;
  const int t = threadIdx.x;
  const int w = t >> 6, lane = t & 63;
  const int g = lane >> 4, c = lane & 15;
  const int q0 = blockIdx.x * 64 + w * 16;

  const u16* Qb = Qh + (size_t)bh * (2048 * 64);
  const u16* Kb = Kh + (size_t)bh * (2048 * 64);
  const u16* Vb = Vt + (size_t)bh * (64 * 2048);

  // Q fragment with per-row temperature folded in (A-frag row = c)
  const float rs = rscale[b * 2048 + q0 + c];
  bf16x8 qf0, qf1;
  {
    const u16x8 a0 = *(const u16x8*)(Qb + (size_t)(q0 + c) * 64 + g * 8);
    const u16x8 a1 = *(const u16x8*)(Qb + (size_t)(q0 + c) * 64 + 32 + g * 8);
    u16x8 o0, o1;
#pragma unroll
    for (int j = 0; j < 8; ++j) {
      o0[j] = f2b(__builtin_bit_cast(float, (u32)a0[j] << 16) * rs);
      o1[j] = f2b(__builtin_bit_cast(float, (u32)a1[j] << 16) * rs);
    }
    qf0 = __builtin_bit_cast(bf16x8, o0);
    qf1 = __builtin_bit_cast(bf16x8, o1);
  }

  float m[4], l[4];
#pragma unroll
  for (int r = 0; r < 4; ++r) { m[r] = -3.0e38f; l[r] = 0.0f; }
  f32x4 acc[4] = {};
  u16 (* const Pw)[72] = Pl[w];

  for (int kc = 0; kc < 2048; kc += 64) {
    // QK^T: 4 sub-tiles of 16 keys (B-frag: col=key, k=d)
    f32x4 s[4];
#pragma unroll
    for (int j = 0; j < 4; ++j) {
      const u16* Kp = Kb + (size_t)(kc + j * 16 + c) * 64 + g * 8;
      const bf16x8 k0 = *(const bf16x8*)(Kp);
      const bf16x8 k1 = *(const bf16x8*)(Kp + 32);
      const f32x4 z = {};
      s[j] = __builtin_amdgcn_mfma_f32_16x16x32_bf16(qf0, k0, z, 0, 0, 0);
      s[j] = __builtin_amdgcn_mfma_f32_16x16x32_bf16(qf1, k1, s[j], 0, 0, 0);
    }

    // V frags (independent of softmax; issue early to hide L2 latency)
    bf16x8 vf[4][2];
#pragma unroll
    for (int dt = 0; dt < 4; ++dt)
#pragma unroll
      for (int kk = 0; kk < 2; ++kk)
        vf[dt][kk] = *(const bf16x8*)(Vb + (size_t)(dt * 16 + c) * 2048 + kc + kk * 32 + g * 8);

    // defer-max: lane-local max + one ballot; tree only on rare growth
    float tl[4];
    bool need = false;
#pragma unroll
    for (int r = 0; r < 4; ++r) {
      tl[r] = fmaxf(fmaxf(s[0][r], s[1][r]), fmaxf(s[2][r], s[3][r]));
      need |= (tl[r] > m[r] + 8.0f);
    }
    if (__any(need)) {
#pragma unroll
      for (int d = 1; d < 16; d <<= 1)
#pragma unroll
        for (int r = 0; r < 4; ++r)
          tl[r] = fmaxf(tl[r], __shfl_xor(tl[r], d));
#pragma unroll
      for (int r = 0; r < 4; ++r) {
        const float mn = fmaxf(m[r], tl[r]);
        const float corr = __builtin_amdgcn_exp2f(m[r] - mn);
        m[r] = mn;
        l[r] *= corr;
#pragma unroll
        for (int dt = 0; dt < 4; ++dt) acc[dt][r] *= corr;
      }
    }

    // P = exp2(s - m) (bounded by 2^8), lane-local l accum, LDS bounce
#pragma unroll
    for (int j = 0; j < 4; ++j)
#pragma unroll
      for (int r = 0; r < 4; ++r) {
        const float p = __builtin_amdgcn_exp2f(s[j][r] - m[r]);
        l[r] += p;
        Pw[g * 4 + r][j * 16 + c] = f2b(p);  // D-layout -> A-frag layout
      }
    const bf16x8 pA0 = *(const bf16x8*)&Pw[c][g * 8];
    const bf16x8 pA1 = *(const bf16x8*)&Pw[c][32 + g * 8];
#pragma unroll
    for (int dt = 0; dt < 4; ++dt) {
      acc[dt] = __builtin_amdgcn_mfma_f32_16x16x32_bf16(pA0, vf[dt][0], acc[dt], 0, 0, 0);
      acc[dt] = __builtin_amdgcn_mfma_f32_16x16x32_bf16(pA1, vf[dt][1], acc[dt], 0, 0, 0);
    }
  }

  // single end-of-loop l reduction across the 16 lanes of each row group
#pragma unroll
  for (int d = 1; d < 16; d <<= 1)
#pragma unroll
    for (int r = 0; r < 4; ++r)
      l[r] += __shfl_xor(l[r], d);

  float inv[4];
#pragma unroll
  for (int r = 0; r < 4; ++r) inv[r] = 1.0f / l[r];
#pragma unroll
  for (int dt = 0; dt < 4; ++dt)
#pragma unroll
    for (int r = 0; r < 4; ++r) {
      const int trow = q0 + g * 4 + r;
      const int dd = dt * 16 + c;
      // Oh layout [b][t][h][d] == flat [m][1024] for the output GEMM
      Oh[(((size_t)b * 2048 + trow) * 16 + h) * 64 + dd] = f2b(acc[dt][r] * inv[r]);
    }
}

// ---------------- launch --------------------------------------------------
extern "C" void kernel_launch(void* const* d_in, const int* in_sizes, int n_in,
                              void* d_out, int out_size, void* d_ws, size_t ws_size,
                              hipStream_t stream) {
  const float* query = (const float*)d_in[0];
  const float* key_  = (const float*)d_in[1];
  const float* value = (const float*)d_in[2];
  const float* phi   = (const float*)d_in[3];
  // d_in[4] logvar: cancels in softmax (additive per-query bias)
  const float* Wq = (const float*)d_in[5];
  const float* bq = (const float*)d_in[6];
  const float* Wk = (const float*)d_in[7];
  const float* bk = (const float*)d_in[8];
  const float* Wv = (const float*)d_in[9];
  const float* bv = (const float*)d_in[10];
  const float* Wo = (const float*)d_in[11];
  const float* bo = (const float*)d_in[12];
  // d_in[13] w_sigma, d_in[14] w_phi: cancel in softmax

  char* ws = (char*)d_ws;
  const size_t MB = 1u << 20;
  u16* Xq  = (u16*)(ws);             // 8MB; reused as Oh after QKV GEMM
  u16* Xk  = (u16*)(ws + 8 * MB);    // 8MB; reused as Vt after QKV GEMM
  u16* Xv  = (u16*)(ws + 16 * MB);   // 8MB
  u16* Wqb = (u16*)(ws + 24 * MB);   // 2MB each
  u16* Wkb = (u16*)(ws + 26 * MB);
  u16* Wvb = (u16*)(ws + 28 * MB);
  u16* Wob = (u16*)(ws + 30 * MB);
  u16* Qh  = (u16*)(ws + 32 * MB);   // 8MB each
  u16* Kh  = (u16*)(ws + 40 * MB);
  u16* Vh  = (u16*)(ws + 48 * MB);
  float* rscale = (float*)(ws + 56 * MB);  // 16KB
  u16* Oh = Xq;
  u16* Vt = Xk;

  prep_kernel<<<16384, 256, 0, stream>>>(query, key_, value, Wq, Wk, Wv, Wo, phi,
                                         Xq, Xk, Xv, Wqb, Wkb, Wvb, Wob, rscale);
  gemm_qkv_kernel<<<dim3(8, 32, 3), 256, 0, stream>>>(Xq, Xk, Xv, Wqb, Wkb, Wvb,
                                                      bq, bk, bv, Qh, Kh, Vh);
  transpose_v_kernel<<<dim3(32, 32), 256, 0, stream>>>(Vh, Vt);
  attn_kernel<<<dim3(32, 32), 256, 0, stream>>>(Qh, Kh, Vt, rscale, Oh);
  gemm_o_kernel<<<dim3(8, 32), 256, 0, stream>>>(Oh, Wob, bo, (float*)d_out);
}

// Round 4
// 287.976 us; speedup vs baseline: 1.5173x; 1.5077x over previous
//
#include <hip/hip_runtime.h>

// ud_MultiheadSoftmaxAttention: B=2 T=2048 D=1024 H=16 hd=64
// Pipeline: prep(fp32->bf16 + row scales) -> batched QKV GEMM (bf16 MFMA)
//           -> V transpose -> flash attention (LDS-staged K/V, dbuf prefetch)
//           -> output GEMM.
// Per-query additive score biases (logvar/w_phi terms) cancel in softmax;
// only the per-row temperature 1/(8*max(mean(phi),1e-6)) survives.

typedef __bf16 bf16x8 __attribute__((ext_vector_type(8)));
typedef float f32x4 __attribute__((ext_vector_type(4)));
typedef unsigned short u16;
typedef unsigned int u32;
typedef u16 u16x8 __attribute__((ext_vector_type(8)));

#define GLD_TO_LDS(g, l) __builtin_amdgcn_global_load_lds( \
    (const __attribute__((address_space(1))) void*)(g),    \
    (__attribute__((address_space(3))) void*)(l), 16, 0, 0)

__device__ __forceinline__ u16 f2b(float f) {
  u32 u = __builtin_bit_cast(u32, f);
  u += 0x7fffu + ((u >> 16) & 1u);   // RNE
  return (u16)(u >> 16);
}

// ---------------- prep: fp32 -> bf16 conversions + softmax row scales ----
__global__ __launch_bounds__(256) void prep_kernel(
    const float* __restrict__ query, const float* __restrict__ key,
    const float* __restrict__ value, const float* __restrict__ Wq,
    const float* __restrict__ Wk, const float* __restrict__ Wv,
    const float* __restrict__ Wo, const float* __restrict__ phi,
    u16* __restrict__ Xq, u16* __restrict__ Xk, u16* __restrict__ Xv,
    u16* __restrict__ Wqb, u16* __restrict__ Wkb, u16* __restrict__ Wvb,
    u16* __restrict__ Wob, float* __restrict__ rscale)
{
  const long gid = (long)blockIdx.x * 256 + threadIdx.x;  // 0..4M-1
  const long e = gid * 4;
  const float* src; u16* dst; long off;
  if (e < 4194304L)       { src = query; dst = Xq;  off = e; }
  else if (e < 8388608L)  { src = key;   dst = Xk;  off = e - 4194304L; }
  else if (e < 12582912L) { src = value; dst = Xv;  off = e - 8388608L; }
  else if (e < 13631488L) { src = Wq;    dst = Wqb; off = e - 12582912L; }
  else if (e < 14680064L) { src = Wk;    dst = Wkb; off = e - 13631488L; }
  else if (e < 15728640L) { src = Wv;    dst = Wvb; off = e - 14680064L; }
  else                    { src = Wo;    dst = Wob; off = e - 15728640L; }
  const float4 v = *(const float4*)(src + off);
  ushort4 o;
  o.x = f2b(v.x); o.y = f2b(v.y); o.z = f2b(v.z); o.w = f2b(v.w);
  *(ushort4*)(dst + off) = o;

  if (gid < 4096) {  // per-token softmax temperature (log2e folded in)
    const float4 p0 = *(const float4*)(phi + gid * 8);
    const float4 p1 = *(const float4*)(phi + gid * 8 + 4);
    const float mean = (p0.x + p0.y + p0.z + p0.w + p1.x + p1.y + p1.z + p1.w) * 0.125f;
    rscale[gid] = 1.4426950408889634f / (8.0f * fmaxf(mean, 1e-6f));
  }
}

// ---------------- GEMM: C[m][n] = A[m][:] . Bw[n][:] + bias[n] -----------
// 128x128 tile, BK=32, 256 thr (4 waves 2x2), global_load_lds width-16.
// MODE 0: bf16 out in per-head layout [b][h][t][64]; MODE 1: f32 flat out.
template<int MODE>
__device__ __forceinline__ void gemm_body(
    u16* As, u16* Bs,
    const u16* __restrict__ A, const u16* __restrict__ Bw,
    const float* __restrict__ bias, void* __restrict__ Cout)
{
  constexpr int K = 1024;
  const int t = threadIdx.x;
  const int lane = t & 63, w = t >> 6;
  const int g = lane >> 4, c = lane & 15;
  const int m0 = blockIdx.y * 128, n0 = blockIdx.x * 128;
  const int srow = t >> 2, skc = (t & 3) * 8;
  const u16* gA = A + (size_t)(m0 + srow) * K + skc;
  const u16* gB = Bw + (size_t)(n0 + srow) * K + skc;
  u16* ldsA = As + w * 512;   // wave-uniform base; HW adds lane*16B
  u16* ldsB = Bs + w * 512;
  const int wm = (w >> 1) * 64, wn = (w & 1) * 64;

  f32x4 acc[4][4] = {};

  for (int k0 = 0; k0 < K; k0 += 32) {
    GLD_TO_LDS(gA + k0, ldsA);
    GLD_TO_LDS(gA + 64 * K + k0, ldsA + 2048);
    GLD_TO_LDS(gB + k0, ldsB);
    GLD_TO_LDS(gB + 64 * K + k0, ldsB + 2048);
    __syncthreads();
    bf16x8 af[4], bfr[4];
#pragma unroll
    for (int mi = 0; mi < 4; ++mi)
      af[mi] = *(const bf16x8*)(As + (wm + mi * 16 + c) * 32 + g * 8);
#pragma unroll
    for (int ni = 0; ni < 4; ++ni)
      bfr[ni] = *(const bf16x8*)(Bs + (wn + ni * 16 + c) * 32 + g * 8);
#pragma unroll
    for (int mi = 0; mi < 4; ++mi)
#pragma unroll
      for (int ni = 0; ni < 4; ++ni)
        acc[mi][ni] = __builtin_amdgcn_mfma_f32_16x16x32_bf16(
            af[mi], bfr[ni], acc[mi][ni], 0, 0, 0);
    __syncthreads();
  }

#pragma unroll
  for (int ni = 0; ni < 4; ++ni) {
    const int ncol = n0 + wn + ni * 16 + c;
    const float bv = bias[ncol];
#pragma unroll
    for (int mi = 0; mi < 4; ++mi) {
#pragma unroll
      for (int r = 0; r < 4; ++r) {
        const int mrow = m0 + wm + mi * 16 + g * 4 + r;  // C/D: col=lane&15, row=(lane>>4)*4+r
        const float val = acc[mi][ni][r] + bv;
        if (MODE == 0) {
          const int bb = mrow >> 11, tt = mrow & 2047;
          const int hh = ncol >> 6, dd = ncol & 63;
          ((u16*)Cout)[((((size_t)bb * 16 + hh) * 2048 + tt) << 6) + dd] = f2b(val);
        } else {
          ((float*)Cout)[(size_t)mrow * 1024 + ncol] = val;
        }
      }
    }
  }
}

__global__ __launch_bounds__(256) void gemm_qkv_kernel(
    const u16* __restrict__ Xq, const u16* __restrict__ Xk, const u16* __restrict__ Xv,
    const u16* __restrict__ Wqb, const u16* __restrict__ Wkb, const u16* __restrict__ Wvb,
    const float* __restrict__ bq, const float* __restrict__ bk, const float* __restrict__ bv,
    u16* __restrict__ Qh, u16* __restrict__ Kh, u16* __restrict__ Vh)
{
  __shared__ __align__(16) u16 As[4096], Bs[4096];
  const int z = blockIdx.z;
  const u16* A = (z == 0) ? Xq : (z == 1) ? Xk : Xv;
  const u16* W = (z == 0) ? Wqb : (z == 1) ? Wkb : Wvb;
  const float* bias = (z == 0) ? bq : (z == 1) ? bk : bv;
  u16* C = (z == 0) ? Qh : (z == 1) ? Kh : Vh;
  gemm_body<0>(As, Bs, A, W, bias, C);
}

__global__ __launch_bounds__(256) void gemm_o_kernel(
    const u16* __restrict__ Oh, const u16* __restrict__ Wob,
    const float* __restrict__ bo, float* __restrict__ out)
{
  __shared__ __align__(16) u16 As[4096], Bs[4096];
  gemm_body<1>(As, Bs, Oh, Wob, bo, out);
}

// ---------------- V transpose: [bh][t][64] -> [bh][64][t] ----------------
__global__ __launch_bounds__(256) void transpose_v_kernel(
    const u16* __restrict__ Vh, u16* __restrict__ Vt)
{
  __shared__ __align__(16) u16 tile[64][72];
  const int bh = blockIdx.y, t0 = blockIdx.x * 64;
  const int tid = threadIdx.x;
  const int r = tid >> 3, cc = (tid & 7) * 8;
  const u16* src = Vh + ((size_t)bh * 2048 + t0) * 64;
#pragma unroll
  for (int it = 0; it < 2; ++it)
    *(u16x8*)&tile[r + 32 * it][cc] = *(const u16x8*)(src + (size_t)(r + 32 * it) * 64 + cc);
  __syncthreads();
  u16* dst = Vt + (size_t)bh * 64 * 2048 + t0;
#pragma unroll
  for (int it = 0; it < 2; ++it) {
    const int d = r + 32 * it;
    u16x8 v;
#pragma unroll
    for (int j = 0; j < 8; ++j) v[j] = tile[cc + j][d];
    *(u16x8*)(dst + (size_t)d * 2048 + cc) = v;
  }
}

// ---------------- flash attention ----------------------------------------
// grid 1024 blocks (XCD-swizzled), 256 thr = 4 waves, 16 q-rows each, KB=64.
// K-tile (64x64) and V^T-tile (64x64) staged cooperatively into LDS via
// global_load_lds (coalesced; XOR-swizzle applied on the per-lane GLOBAL
// source so swizzled ds_read_b128 is conflict-balanced). Double-buffered,
// depth-2 prefetch with counted vmcnt(4) + raw barriers (no vmcnt(0) drain
// in steady state). Defer-max softmax, lane-local l, P via swizzled LDS.
__global__ __launch_bounds__(256) void attn_kernel(
    const u16* __restrict__ Qh, const u16* __restrict__ Kh,
    const u16* __restrict__ Vt, const float* __restrict__ rscale,
    u16* __restrict__ Oh)
{
  __shared__ __align__(16) u16 Ks[2][4096];  // [buf][64 keys][64 d], swizzled
  __shared__ __align__(16) u16 Vs[2][4096];  // [buf][64 d][64 keys], swizzled
  __shared__ __align__(16) u16 Pl[4][1024];  // per-wave 16x64, swizzled
  // total LDS = 40960 B -> 4 blocks/CU

  // bijective XCD remap: group 4 consecutive bh per XCD so K/V stay L2-resident
  const u32 orig = blockIdx.y * 32 + blockIdx.x;   // HW dispatch-linear id
  const u32 newL = (orig & 7u) * 128u + (orig >> 3);
  const int qx = newL & 31, bh = newL >> 5;
  const int b = bh >> 4, h = bh & 15;

  const int t = threadIdx.x;
  const int w = t >> 6, lane = t & 63;
  const int g = lane >> 4, c = lane & 15;
  const int q0 = qx * 64 + w * 16;
  const int swz = (c & 7) << 4;          // read-side XOR swizzle (byte units)

  const u16* Qb = Qh + (size_t)bh * (2048 * 64);
  const u16* Kb = Kh + (size_t)bh * (2048 * 64);
  const u16* Vb = Vt + (size_t)bh * (64 * 2048);

  // staging geometry: 256 thr x 16B = 4KB/instr = 32 rows x 128B
  const int sr = t >> 3;                       // row 0..31 (= w*8 + lane/8)
  const int sx = ((t & 7) ^ (sr & 7)) * 8;     // inverse-swizzled u16 col

  // Q fragment with per-row temperature folded in (A-frag row = c)
  const float rs = rscale[b * 2048 + q0 + c];
  bf16x8 qf0, qf1;
  {
    const u16x8 a0 = *(const u16x8*)(Qb + (size_t)(q0 + c) * 64 + g * 8);
    const u16x8 a1 = *(const u16x8*)(Qb + (size_t)(q0 + c) * 64 + 32 + g * 8);
    u16x8 o0, o1;
#pragma unroll
    for (int j = 0; j < 8; ++j) {
      o0[j] = f2b(__builtin_bit_cast(float, (u32)a0[j] << 16) * rs);
      o1[j] = f2b(__builtin_bit_cast(float, (u32)a1[j] << 16) * rs);
    }
    qf0 = __builtin_bit_cast(bf16x8, o0);
    qf1 = __builtin_bit_cast(bf16x8, o1);
  }

  float m[4], l[4];
#pragma unroll
  for (int r = 0; r < 4; ++r) { m[r] = -3.0e38f; l[r] = 0.0f; }
  f32x4 acc[4] = {};
  u16* const Pw = &Pl[w][0];

#define STAGE(buf_, kc_) do {                                         \
    const u16* kg0 = Kb + (size_t)((kc_) + sr) * 64 + sx;             \
    const u16* kg1 = Kb + (size_t)((kc_) + 32 + sr) * 64 + sx;        \
    const u16* vg0 = Vb + (size_t)sr * 2048 + (kc_) + sx;             \
    const u16* vg1 = Vb + (size_t)(32 + sr) * 2048 + (kc_) + sx;      \
    u16* kd = &Ks[buf_][w * 512];                                     \
    u16* vd = &Vs[buf_][w * 512];                                     \
    GLD_TO_LDS(kg0, kd);                                              \
    GLD_TO_LDS(kg1, kd + 2048);                                       \
    GLD_TO_LDS(vg0, vd);                                              \
    GLD_TO_LDS(vg1, vd + 2048);                                       \
  } while (0)

  STAGE(0, 0);

  for (int kc = 0; kc < 2048; kc += 64) {
    const int buf = (kc >> 6) & 1;
    if (kc + 64 < 2048) {
      STAGE(buf ^ 1, kc + 64);
      asm volatile("s_waitcnt vmcnt(4)" ::: "memory");  // drain current tile only
    } else {
      asm volatile("s_waitcnt vmcnt(0)" ::: "memory");
    }
    __builtin_amdgcn_s_barrier();

    const u16* Kt = &Ks[buf][0];
    const u16* Vq = &Vs[buf][0];

    // QK^T: 4 sub-tiles of 16 keys (B-frag: col=key, k=d), from swizzled LDS
    f32x4 s[4];
#pragma unroll
    for (int j = 0; j < 4; ++j) {
      const int rk = j * 16 + c;
      const bf16x8 k0 = *(const bf16x8*)(Kt + rk * 64 + ((((g << 4)) ^ swz) >> 1));
      const bf16x8 k1 = *(const bf16x8*)(Kt + rk * 64 + (((64 | (g << 4)) ^ swz) >> 1));
      const f32x4 z = {};
      s[j] = __builtin_amdgcn_mfma_f32_16x16x32_bf16(qf0, k0, z, 0, 0, 0);
      s[j] = __builtin_amdgcn_mfma_f32_16x16x32_bf16(qf1, k1, s[j], 0, 0, 0);
    }

    // V frags from swizzled LDS (independent of softmax)
    bf16x8 vf[4][2];
#pragma unroll
    for (int dt = 0; dt < 4; ++dt) {
      const int rv = dt * 16 + c;
#pragma unroll
      for (int kk = 0; kk < 2; ++kk)
        vf[dt][kk] = *(const bf16x8*)(Vq + rv * 64 + ((((kk << 6) | (g << 4)) ^ swz) >> 1));
    }

    // defer-max: lane-local max + one ballot; tree only on rare growth
    float tl[4];
    bool need = false;
#pragma unroll
    for (int r = 0; r < 4; ++r) {
      tl[r] = fmaxf(fmaxf(s[0][r], s[1][r]), fmaxf(s[2][r], s[3][r]));
      need |= (tl[r] > m[r] + 8.0f);
    }
    if (__any(need)) {
#pragma unroll
      for (int d = 1; d < 16; d <<= 1)
#pragma unroll
        for (int r = 0; r < 4; ++r)
          tl[r] = fmaxf(tl[r], __shfl_xor(tl[r], d));
#pragma unroll
      for (int r = 0; r < 4; ++r) {
        const float mn = fmaxf(m[r], tl[r]);
        const float corr = __builtin_amdgcn_exp2f(m[r] - mn);
        m[r] = mn;
        l[r] *= corr;
#pragma unroll
        for (int dt = 0; dt < 4; ++dt) acc[dt][r] *= corr;
      }
    }

    // P = exp2(s - m) (bounded by 2^8); D-layout -> swizzled LDS -> A-frag
#pragma unroll
    for (int j = 0; j < 4; ++j)
#pragma unroll
      for (int r = 0; r < 4; ++r) {
        const float p = __builtin_amdgcn_exp2f(s[j][r] - m[r]);
        l[r] += p;
        const int prow = g * 4 + r;
        Pw[prow * 64 + ((((j * 16 + c) * 2) ^ ((prow & 7) << 4)) >> 1)] = f2b(p);
      }
    const bf16x8 pA0 = *(const bf16x8*)(Pw + c * 64 + (((0 | (g << 4)) ^ swz) >> 1));
    const bf16x8 pA1 = *(const bf16x8*)(Pw + c * 64 + (((64 | (g << 4)) ^ swz) >> 1));
#pragma unroll
    for (int dt = 0; dt < 4; ++dt) {
      acc[dt] = __builtin_amdgcn_mfma_f32_16x16x32_bf16(pA0, vf[dt][0], acc[dt], 0, 0, 0);
      acc[dt] = __builtin_amdgcn_mfma_f32_16x16x32_bf16(pA1, vf[dt][1], acc[dt], 0, 0, 0);
    }

    __builtin_amdgcn_s_barrier();   // reads of buf done before next stage overwrites
  }
#undef STAGE

  // single end-of-loop l reduction across the 16 lanes of each row group
#pragma unroll
  for (int d = 1; d < 16; d <<= 1)
#pragma unroll
    for (int r = 0; r < 4; ++r)
      l[r] += __shfl_xor(l[r], d);

  float inv[4];
#pragma unroll
  for (int r = 0; r < 4; ++r) inv[r] = 1.0f / l[r];
#pragma unroll
  for (int dt = 0; dt < 4; ++dt)
#pragma unroll
    for (int r = 0; r < 4; ++r) {
      const int trow = q0 + g * 4 + r;
      const int dd = dt * 16 + c;
      // Oh layout [b][t][h][d] == flat [m][1024] for the output GEMM
      Oh[(((size_t)b * 2048 + trow) * 16 + h) * 64 + dd] = f2b(acc[dt][r] * inv[r]);
    }
}

// ---------------- launch --------------------------------------------------
extern "C" void kernel_launch(void* const* d_in, const int* in_sizes, int n_in,
                              void* d_out, int out_size, void* d_ws, size_t ws_size,
                              hipStream_t stream) {
  const float* query = (const float*)d_in[0];
  const float* key_  = (const float*)d_in[1];
  const float* value = (const float*)d_in[2];
  const float* phi   = (const float*)d_in[3];
  // d_in[4] logvar: cancels in softmax (additive per-query bias)
  const float* Wq = (const float*)d_in[5];
  const float* bq = (const float*)d_in[6];
  const float* Wk = (const float*)d_in[7];
  const float* bk = (const float*)d_in[8];
  const float* Wv = (const float*)d_in[9];
  const float* bv = (const float*)d_in[10];
  const float* Wo = (const float*)d_in[11];
  const float* bo = (const float*)d_in[12];
  // d_in[13] w_sigma, d_in[14] w_phi: cancel in softmax

  char* ws = (char*)d_ws;
  const size_t MB = 1u << 20;
  u16* Xq  = (u16*)(ws);             // 8MB; reused as Oh after QKV GEMM
  u16* Xk  = (u16*)(ws + 8 * MB);    // 8MB; reused as Vt after QKV GEMM
  u16* Xv  = (u16*)(ws + 16 * MB);   // 8MB
  u16* Wqb = (u16*)(ws + 24 * MB);   // 2MB each
  u16* Wkb = (u16*)(ws + 26 * MB);
  u16* Wvb = (u16*)(ws + 28 * MB);
  u16* Wob = (u16*)(ws + 30 * MB);
  u16* Qh  = (u16*)(ws + 32 * MB);   // 8MB each
  u16* Kh  = (u16*)(ws + 40 * MB);
  u16* Vh  = (u16*)(ws + 48 * MB);
  float* rscale = (float*)(ws + 56 * MB);  // 16KB
  u16* Oh = Xq;
  u16* Vt = Xk;

  prep_kernel<<<16384, 256, 0, stream>>>(query, key_, value, Wq, Wk, Wv, Wo, phi,
                                         Xq, Xk, Xv, Wqb, Wkb, Wvb, Wob, rscale);
  gemm_qkv_kernel<<<dim3(8, 32, 3), 256, 0, stream>>>(Xq, Xk, Xv, Wqb, Wkb, Wvb,
                                                      bq, bk, bv, Qh, Kh, Vh);
  transpose_v_kernel<<<dim3(32, 32), 256, 0, stream>>>(Vh, Vt);
  attn_kernel<<<dim3(32, 32), 256, 0, stream>>>(Qh, Kh, Vt, rscale, Oh);
  gemm_o_kernel<<<dim3(8, 32), 256, 0, stream>>>(Oh, Wob, bo, (float*)d_out);
}

// Round 5
// 258.438 us; speedup vs baseline: 1.6907x; 1.1143x over previous
//
#include <hip/hip_runtime.h>

// ud_MultiheadSoftmaxAttention: B=2 T=2048 D=1024 H=16 hd=64
// Pipeline: prep(fp32->bf16 + row scales) -> batched QKV GEMM (bf16 MFMA,
//           dbuf+counted vmcnt) -> V transpose -> flash attention (LDS-staged
//           K/V, swapped-operand in-register softmax) -> output GEMM.
// Per-query additive score biases (logvar/w_phi terms) cancel in softmax;
// only the per-row temperature 1/(8*max(mean(phi),1e-6)) survives.

typedef __bf16 bf16x8 __attribute__((ext_vector_type(8)));
typedef __bf16 bf16x4 __attribute__((ext_vector_type(4)));
typedef float f32x4 __attribute__((ext_vector_type(4)));
typedef unsigned short u16;
typedef unsigned int u32;
typedef u16 u16x8 __attribute__((ext_vector_type(8)));

#define GLD_TO_LDS(g, l) __builtin_amdgcn_global_load_lds( \
    (const __attribute__((address_space(1))) void*)(g),    \
    (__attribute__((address_space(3))) void*)(l), 16, 0, 0)

__device__ __forceinline__ u16 f2b(float f) {
  u32 u = __builtin_bit_cast(u32, f);
  u += 0x7fffu + ((u >> 16) & 1u);   // RNE
  return (u16)(u >> 16);
}

// ---------------- prep: fp32 -> bf16 conversions + softmax row scales ----
__global__ __launch_bounds__(256) void prep_kernel(
    const float* __restrict__ query, const float* __restrict__ key,
    const float* __restrict__ value, const float* __restrict__ Wq,
    const float* __restrict__ Wk, const float* __restrict__ Wv,
    const float* __restrict__ Wo, const float* __restrict__ phi,
    u16* __restrict__ Xq, u16* __restrict__ Xk, u16* __restrict__ Xv,
    u16* __restrict__ Wqb, u16* __restrict__ Wkb, u16* __restrict__ Wvb,
    u16* __restrict__ Wob, float* __restrict__ rscale)
{
  const long gid = (long)blockIdx.x * 256 + threadIdx.x;  // 0..4M-1
  const long e = gid * 4;
  const float* src; u16* dst; long off;
  if (e < 4194304L)       { src = query; dst = Xq;  off = e; }
  else if (e < 8388608L)  { src = key;   dst = Xk;  off = e - 4194304L; }
  else if (e < 12582912L) { src = value; dst = Xv;  off = e - 8388608L; }
  else if (e < 13631488L) { src = Wq;    dst = Wqb; off = e - 12582912L; }
  else if (e < 14680064L) { src = Wk;    dst = Wkb; off = e - 13631488L; }
  else if (e < 15728640L) { src = Wv;    dst = Wvb; off = e - 14680064L; }
  else                    { src = Wo;    dst = Wob; off = e - 15728640L; }
  const float4 v = *(const float4*)(src + off);
  ushort4 o;
  o.x = f2b(v.x); o.y = f2b(v.y); o.z = f2b(v.z); o.w = f2b(v.w);
  *(ushort4*)(dst + off) = o;

  if (gid < 4096) {  // per-token softmax temperature (log2e folded in)
    const float4 p0 = *(const float4*)(phi + gid * 8);
    const float4 p1 = *(const float4*)(phi + gid * 8 + 4);
    const float mean = (p0.x + p0.y + p0.z + p0.w + p1.x + p1.y + p1.z + p1.w) * 0.125f;
    rscale[gid] = 1.4426950408889634f / (8.0f * fmaxf(mean, 1e-6f));
  }
}

// ---------------- GEMM: C[m][n] = A[m][:] . Bw[n][:] + bias[n] -----------
// 128x128 tile, BK=32, 256 thr (4 waves 2x2), global_load_lds width-16,
// double-buffered LDS + counted vmcnt(4) + raw barriers (no full drain).
// MODE 0: bf16 out in per-head layout [b][h][t][64]; MODE 1: f32 flat out.
template<int MODE>
__device__ __forceinline__ void gemm_body(
    u16 (*As)[4096], u16 (*Bs)[4096], int m0, int n0,
    const u16* __restrict__ A, const u16* __restrict__ Bw,
    const float* __restrict__ bias, void* __restrict__ Cout)
{
  constexpr int K = 1024;
  const int t = threadIdx.x;
  const int lane = t & 63, w = t >> 6;
  const int g = lane >> 4, c = lane & 15;
  const int srow = t >> 2, skc = (t & 3) * 8;
  const u16* gA = A + (size_t)(m0 + srow) * K + skc;
  const u16* gB = Bw + (size_t)(n0 + srow) * K + skc;
  const int wm = (w >> 1) * 64, wn = (w & 1) * 64;

  f32x4 acc[4][4] = {};

#define STG(b_, k0_) do {                              \
    GLD_TO_LDS(gA + (k0_), &As[b_][w * 512]);          \
    GLD_TO_LDS(gA + 64 * K + (k0_), &As[b_][w * 512 + 2048]); \
    GLD_TO_LDS(gB + (k0_), &Bs[b_][w * 512]);          \
    GLD_TO_LDS(gB + 64 * K + (k0_), &Bs[b_][w * 512 + 2048]); \
  } while (0)

  STG(0, 0);
  for (int i = 0; i < 32; ++i) {
    const int buf = i & 1;
    if (i < 31) {
      STG(buf ^ 1, (i + 1) * 32);
      asm volatile("s_waitcnt vmcnt(4)" ::: "memory");  // current tile drained
    } else {
      asm volatile("s_waitcnt vmcnt(0)" ::: "memory");
    }
    __builtin_amdgcn_s_barrier();
    bf16x8 af[4], bfr[4];
#pragma unroll
    for (int mi = 0; mi < 4; ++mi)
      af[mi] = *(const bf16x8*)(&As[buf][0] + (wm + mi * 16 + c) * 32 + g * 8);
#pragma unroll
    for (int ni = 0; ni < 4; ++ni)
      bfr[ni] = *(const bf16x8*)(&Bs[buf][0] + (wn + ni * 16 + c) * 32 + g * 8);
#pragma unroll
    for (int mi = 0; mi < 4; ++mi)
#pragma unroll
      for (int ni = 0; ni < 4; ++ni)
        acc[mi][ni] = __builtin_amdgcn_mfma_f32_16x16x32_bf16(
            af[mi], bfr[ni], acc[mi][ni], 0, 0, 0);
    __builtin_amdgcn_s_barrier();  // reads done before next overwrite
  }
#undef STG

#pragma unroll
  for (int ni = 0; ni < 4; ++ni) {
    const int ncol = n0 + wn + ni * 16 + c;
    const float bv = bias[ncol];
#pragma unroll
    for (int mi = 0; mi < 4; ++mi) {
#pragma unroll
      for (int r = 0; r < 4; ++r) {
        const int mrow = m0 + wm + mi * 16 + g * 4 + r;  // C/D: col=lane&15, row=(lane>>4)*4+r
        const float val = acc[mi][ni][r] + bv;
        if (MODE == 0) {
          const int bb = mrow >> 11, tt = mrow & 2047;
          const int hh = ncol >> 6, dd = ncol & 63;
          ((u16*)Cout)[((((size_t)bb * 16 + hh) * 2048 + tt) << 6) + dd] = f2b(val);
        } else {
          ((float*)Cout)[(size_t)mrow * 1024 + ncol] = val;
        }
      }
    }
  }
}

__global__ __launch_bounds__(256) void gemm_qkv_kernel(
    const u16* __restrict__ Xq, const u16* __restrict__ Xk, const u16* __restrict__ Xv,
    const u16* __restrict__ Wqb, const u16* __restrict__ Wkb, const u16* __restrict__ Wvb,
    const float* __restrict__ bq, const float* __restrict__ bk, const float* __restrict__ bv,
    u16* __restrict__ Qh, u16* __restrict__ Kh, u16* __restrict__ Vh)
{
  __shared__ __align__(16) u16 As[2][4096], Bs[2][4096];
  // bijective chunked XCD remap: 768 blocks = 8 chunks x 96 -> x-siblings
  // (sharing a 256KB A-panel) stay on one XCD's L2.
  const u32 n = blockIdx.z * 256u + blockIdx.y * 8u + blockIdx.x;
  const u32 nl = (n & 7u) * 96u + (n >> 3);
  const int bx = nl & 7, by = (nl >> 3) & 31, bz = nl >> 8;
  const u16* A = (bz == 0) ? Xq : (bz == 1) ? Xk : Xv;
  const u16* W = (bz == 0) ? Wqb : (bz == 1) ? Wkb : Wvb;
  const float* bias = (bz == 0) ? bq : (bz == 1) ? bk : bv;
  u16* C = (bz == 0) ? Qh : (bz == 1) ? Kh : Vh;
  gemm_body<0>(As, Bs, by * 128, bx * 128, A, W, bias, C);
}

__global__ __launch_bounds__(256) void gemm_o_kernel(
    const u16* __restrict__ Oh, const u16* __restrict__ Wob,
    const float* __restrict__ bo, float* __restrict__ out)
{
  __shared__ __align__(16) u16 As[2][4096], Bs[2][4096];
  const u32 n = blockIdx.y * 8u + blockIdx.x;
  const u32 nl = (n & 7u) * 32u + (n >> 3);
  gemm_body<1>(As, Bs, (int)(nl >> 3) * 128, (int)(nl & 7) * 128, Oh, Wob, bo, out);
}

// ---------------- V transpose: [bh][t][64] -> [bh][64][t] ----------------
__global__ __launch_bounds__(256) void transpose_v_kernel(
    const u16* __restrict__ Vh, u16* __restrict__ Vt)
{
  __shared__ __align__(16) u16 tile[64][72];
  const int bh = blockIdx.y, t0 = blockIdx.x * 64;
  const int tid = threadIdx.x;
  const int r = tid >> 3, cc = (tid & 7) * 8;
  const u16* src = Vh + ((size_t)bh * 2048 + t0) * 64;
#pragma unroll
  for (int it = 0; it < 2; ++it)
    *(u16x8*)&tile[r + 32 * it][cc] = *(const u16x8*)(src + (size_t)(r + 32 * it) * 64 + cc);
  __syncthreads();
  u16* dst = Vt + (size_t)bh * 64 * 2048 + t0;
#pragma unroll
  for (int it = 0; it < 2; ++it) {
    const int d = r + 32 * it;
    u16x8 v;
#pragma unroll
    for (int j = 0; j < 8; ++j) v[j] = tile[cc + j][d];
    *(u16x8*)(dst + (size_t)d * 2048 + cc) = v;
  }
}

// ---------------- flash attention ----------------------------------------
// grid 1024 blocks (XCD-swizzled), 256 thr = 4 waves, 16 q-rows each, KB=64.
// K/V staged in LDS (dbuf, counted vmcnt(4)). SWAPPED-OPERAND structure:
// QK^T computed as mfma(K,Q) -> S^T with q = lane&15, so each lane owns one
// query column: m,l are per-lane scalars, softmax fully in-register, and the
// P tile feeds PV (also swapped: O^T = mfma(V^T, P^T)) directly from the D
// registers via a key permutation kappa(g*8+jj) = (jj>>2)*16 + g*4 + (jj&3);
// V^T fragments use 2x ds_read_b64 per 32-key chunk to match. No P LDS.
__global__ __launch_bounds__(256) void attn_kernel(
    const u16* __restrict__ Qh, const u16* __restrict__ Kh,
    const u16* __restrict__ Vt, const float* __restrict__ rscale,
    u16* __restrict__ Oh)
{
  __shared__ __align__(16) u16 Ks[2][4096];  // [buf][64 keys][64 d], swizzled
  __shared__ __align__(16) u16 Vs[2][4096];  // [buf][64 d][64 keys], swizzled
  // total LDS = 32768 B

  // bijective XCD remap: group consecutive bh per XCD so K/V stay L2-resident
  const u32 orig = blockIdx.y * 32 + blockIdx.x;   // HW dispatch-linear id
  const u32 newL = (orig & 7u) * 128u + (orig >> 3);
  const int qx = newL & 31, bh = newL >> 5;
  const int b = bh >> 4, h = bh & 15;

  const int t = threadIdx.x;
  const int w = t >> 6, lane = t & 63;
  const int g = lane >> 4, c = lane & 15;
  const int q0 = qx * 64 + w * 16;
  const int swz = (c & 7) << 4;          // K-read XOR swizzle (rows == c mod 8)

  const u16* Qb = Qh + (size_t)bh * (2048 * 64);
  const u16* Kb = Kh + (size_t)bh * (2048 * 64);
  const u16* Vb = Vt + (size_t)bh * (64 * 2048);

  // staging geometry: 256 thr x 16B = 4KB/instr = 32 rows x 128B
  const int sr = t >> 3;                       // row 0..31
  const int sx = ((t & 7) ^ (sr & 7)) * 8;     // inverse-swizzled u16 col

  // Q fragment (B-operand: col=q=c, k=d) with per-row temperature folded in
  const float rs = rscale[b * 2048 + q0 + c];
  bf16x8 qf0, qf1;
  {
    const u16x8 a0 = *(const u16x8*)(Qb + (size_t)(q0 + c) * 64 + g * 8);
    const u16x8 a1 = *(const u16x8*)(Qb + (size_t)(q0 + c) * 64 + 32 + g * 8);
    u16x8 o0, o1;
#pragma unroll
    for (int j = 0; j < 8; ++j) {
      o0[j] = f2b(__builtin_bit_cast(float, (u32)a0[j] << 16) * rs);
      o1[j] = f2b(__builtin_bit_cast(float, (u32)a1[j] << 16) * rs);
    }
    qf0 = __builtin_bit_cast(bf16x8, o0);
    qf1 = __builtin_bit_cast(bf16x8, o1);
  }

  float m = -3.0e38f, l = 0.0f;   // per-lane scalars (query q0+c)
  f32x4 acc[4] = {};              // acc[dt][r] = O^T[dt*16+g*4+r][q0+c]

#define STAGE(buf_, kc_) do {                                         \
    const u16* kg0 = Kb + (size_t)((kc_) + sr) * 64 + sx;             \
    const u16* kg1 = Kb + (size_t)((kc_) + 32 + sr) * 64 + sx;        \
    const u16* vg0 = Vb + (size_t)sr * 2048 + (kc_) + sx;             \
    const u16* vg1 = Vb + (size_t)(32 + sr) * 2048 + (kc_) + sx;      \
    u16* kd = &Ks[buf_][w * 512];                                     \
    u16* vd = &Vs[buf_][w * 512];                                     \
    GLD_TO_LDS(kg0, kd);                                              \
    GLD_TO_LDS(kg1, kd + 2048);                                       \
    GLD_TO_LDS(vg0, vd);                                              \
    GLD_TO_LDS(vg1, vd + 2048);                                       \
  } while (0)

  STAGE(0, 0);

  for (int kc = 0; kc < 2048; kc += 64) {
    const int buf = (kc >> 6) & 1;
    if (kc + 64 < 2048) {
      STAGE(buf ^ 1, kc + 64);
      asm volatile("s_waitcnt vmcnt(4)" ::: "memory");  // current tile drained
    } else {
      asm volatile("s_waitcnt vmcnt(0)" ::: "memory");
    }
    __builtin_amdgcn_s_barrier();

    const u16* Kt = &Ks[buf][0];
    const u16* Vq = &Vs[buf][0];

    // S^T = mfma(K, Q): s[j][r] = S[key = j*16+g*4+r][q = q0+c]
    f32x4 s[4];
#pragma unroll
    for (int j = 0; j < 4; ++j) {
      const int rk = j * 16 + c;
      const bf16x8 k0 = *(const bf16x8*)(Kt + rk * 64 + ((((g << 4)) ^ swz) >> 1));
      const bf16x8 k1 = *(const bf16x8*)(Kt + rk * 64 + (((64 | (g << 4)) ^ swz) >> 1));
      const f32x4 z = {};
      s[j] = __builtin_amdgcn_mfma_f32_16x16x32_bf16(k0, qf0, z, 0, 0, 0);
      s[j] = __builtin_amdgcn_mfma_f32_16x16x32_bf16(k1, qf1, s[j], 0, 0, 0);
    }

    // defer-max: per-lane max + one ballot; column tree only on rare growth
    float tl = s[0][0];
#pragma unroll
    for (int j = 0; j < 4; ++j)
#pragma unroll
      for (int r = 0; r < 4; ++r) tl = fmaxf(tl, s[j][r]);
    if (__any(tl > m + 8.0f)) {
      tl = fmaxf(tl, __shfl_xor(tl, 16));
      tl = fmaxf(tl, __shfl_xor(tl, 32));
      const float mn = fmaxf(m, tl);
      const float corr = __builtin_amdgcn_exp2f(m - mn);
      m = mn;
      l *= corr;
#pragma unroll
      for (int dt = 0; dt < 4; ++dt)
#pragma unroll
        for (int r = 0; r < 4; ++r) acc[dt][r] *= corr;
    }

    // P = exp2(s - m), lane-local l accum, pack straight into PV B-frags
    float p[4][4];
#pragma unroll
    for (int j = 0; j < 4; ++j)
#pragma unroll
      for (int r = 0; r < 4; ++r) {
        p[j][r] = __builtin_amdgcn_exp2f(s[j][r] - m);
        l += p[j][r];
      }
    bf16x8 pb0, pb1;   // B-frag k-slot g*8+jj holds key kappa=(jj>>2)*16+g*4+(jj&3)
#pragma unroll
    for (int jj = 0; jj < 8; ++jj) {
      pb0[jj] = (__bf16)p[jj >> 2][jj & 3];
      pb1[jj] = (__bf16)p[2 + (jj >> 2)][jj & 3];
    }

    // PV (swapped): acc[dt] += mfma(V^T-frag, P^T-frag); V^T A-frag k-slots
    // follow kappa -> two 8B chunks per 32-key mfma.
#pragma unroll
    for (int dt = 0; dt < 4; ++dt) {
      const int rv = dt * 16 + c;
      const u16* vrow = Vq + rv * 64;
      const int xr = (rv & 7) << 4;
      bf16x8 va0, va1;
      const bf16x4 a0 = *(const bf16x4*)(vrow + (((g * 8) ^ xr) >> 1));
      const bf16x4 a1 = *(const bf16x4*)(vrow + (((32 + g * 8) ^ xr) >> 1));
      const bf16x4 a2 = *(const bf16x4*)(vrow + (((64 + g * 8) ^ xr) >> 1));
      const bf16x4 a3 = *(const bf16x4*)(vrow + (((96 + g * 8) ^ xr) >> 1));
#pragma unroll
      for (int j = 0; j < 4; ++j) {
        va0[j] = a0[j]; va0[4 + j] = a1[j];
        va1[j] = a2[j]; va1[4 + j] = a3[j];
      }
      acc[dt] = __builtin_amdgcn_mfma_f32_16x16x32_bf16(va0, pb0, acc[dt], 0, 0, 0);
      acc[dt] = __builtin_amdgcn_mfma_f32_16x16x32_bf16(va1, pb1, acc[dt], 0, 0, 0);
    }

    __builtin_amdgcn_s_barrier();   // reads of buf done before next overwrite
  }
#undef STAGE

  // column l: sum the 4 g-partials of each query column (once)
  l += __shfl_xor(l, 16);
  l += __shfl_xor(l, 32);
  const float inv = 1.0f / l;

#pragma unroll
  for (int dt = 0; dt < 4; ++dt)
#pragma unroll
    for (int r = 0; r < 4; ++r) {
      const int trow = q0 + c;
      const int dd = dt * 16 + g * 4 + r;
      // Oh layout [b][t][h][d] == flat [m][1024] for the output GEMM
      Oh[(((size_t)b * 2048 + trow) * 16 + h) * 64 + dd] = f2b(acc[dt][r] * inv);
    }
}

// ---------------- launch --------------------------------------------------
extern "C" void kernel_launch(void* const* d_in, const int* in_sizes, int n_in,
                              void* d_out, int out_size, void* d_ws, size_t ws_size,
                              hipStream_t stream) {
  const float* query = (const float*)d_in[0];
  const float* key_  = (const float*)d_in[1];
  const float* value = (const float*)d_in[2];
  const float* phi   = (const float*)d_in[3];
  // d_in[4] logvar: cancels in softmax (additive per-query bias)
  const float* Wq = (const float*)d_in[5];
  const float* bq = (const float*)d_in[6];
  const float* Wk = (const float*)d_in[7];
  const float* bk = (const float*)d_in[8];
  const float* Wv = (const float*)d_in[9];
  const float* bv = (const float*)d_in[10];
  const float* Wo = (const float*)d_in[11];
  const float* bo = (const float*)d_in[12];
  // d_in[13] w_sigma, d_in[14] w_phi: cancel in softmax

  char* ws = (char*)d_ws;
  const size_t MB = 1u << 20;
  u16* Xq  = (u16*)(ws);             // 8MB; reused as Oh after QKV GEMM
  u16* Xk  = (u16*)(ws + 8 * MB);    // 8MB; reused as Vt after QKV GEMM
  u16* Xv  = (u16*)(ws + 16 * MB);   // 8MB
  u16* Wqb = (u16*)(ws + 24 * MB);   // 2MB each
  u16* Wkb = (u16*)(ws + 26 * MB);
  u16* Wvb = (u16*)(ws + 28 * MB);
  u16* Wob = (u16*)(ws + 30 * MB);
  u16* Qh  = (u16*)(ws + 32 * MB);   // 8MB each
  u16* Kh  = (u16*)(ws + 40 * MB);
  u16* Vh  = (u16*)(ws + 48 * MB);
  float* rscale = (float*)(ws + 56 * MB);  // 16KB
  u16* Oh = Xq;
  u16* Vt = Xk;

  prep_kernel<<<16384, 256, 0, stream>>>(query, key_, value, Wq, Wk, Wv, Wo, phi,
                                         Xq, Xk, Xv, Wqb, Wkb, Wvb, Wob, rscale);
  gemm_qkv_kernel<<<dim3(8, 32, 3), 256, 0, stream>>>(Xq, Xk, Xv, Wqb, Wkb, Wvb,
                                                      bq, bk, bv, Qh, Kh, Vh);
  transpose_v_kernel<<<dim3(32, 32), 256, 0, stream>>>(Vh, Vt);
  attn_kernel<<<dim3(32, 32), 256, 0, stream>>>(Qh, Kh, Vt, rscale, Oh);
  gemm_o_kernel<<<dim3(8, 32), 256, 0, stream>>>(Oh, Wob, bo, (float*)d_out);
}